// Round 4
// baseline (459.261 us; speedup 1.0000x reference)
//
#include <hip/hip_runtime.h>
#include <hip/hip_bf16.h>

#define Bn 8
#define Qn 300
#define Pn 5
#define RSn 256
#define QSn 768
#define NCn 396
#define MTOT 10880
#define THRL -1.3862943611198906f   // log(0.2/0.8): sigmoid(x)>0.2 <=> x>THRL

typedef __attribute__((ext_vector_type(8))) short short8;
typedef __attribute__((ext_vector_type(4))) float float4v;

__device__ inline float wred(float v){
  #pragma unroll
  for (int off = 32; off; off >>= 1) v += __shfl_xor(v, off);
  return v;
}

__device__ inline float bf2f(unsigned short u){
  union { unsigned int i; float f; } c; c.i = ((unsigned int)u) << 16; return c.f;
}

// =====================================================================
// D1: k_front — blocks [0,768): convW f32->bf16 ; [768,800): mask detect ;
//               [800,840): query pooling
// =====================================================================
__global__ void k_front(const float* cw0, const float* cw1, const float* cw2, const float* cw3,
                        __hip_bfloat16* Wb, const int* __restrict__ m0, int* det,
                        const float* __restrict__ pl, const float* __restrict__ hs,
                        float* pooled, int* flags){
  int bx = blockIdx.x;
  if (bx < 768){
    int s = bx / 192;
    int off = (bx % 192)*1024 + threadIdx.x*4;
    const float* src = (s==0)?cw0:(s==1)?cw1:(s==2)?cw2:cw3;
    __hip_bfloat16* dst = Wb + (size_t)s*768*256;
    #pragma unroll
    for (int i = 0; i < 4; ++i) dst[off+i] = __float2bfloat16(src[off+i]);
    return;
  }
  if (bx < 800){
    int i = (bx - 768) * 256 + threadIdx.x;   // 8192 ints = 32KB, safe under all layouts
    int v = m0[i];
    if (v != 0 && v != 1) atomicOr(&det[0], 1);
    if (v != 0 && v != 0x3F800000) atomicOr(&det[1], 1);
    return;
  }
  // ---- query pooling
  __shared__ float msk[Qn];
  int bb = (bx - 800) / Pn, p = (bx - 800) % Pn;
  int t = threadIdx.x;
  for (int q = t; q < Qn; q += 256)
    msk[q] = (pl[(bb*Qn + q)*Pn + p] > THRL) ? 1.f : 0.f;
  __syncthreads();
  const float* hb = hs + (size_t)bb*Qn*RSn + t;
  float ssum = 0.f, cnt = 0.f;
  for (int q = 0; q < Qn; ++q){
    float m = msk[q];
    cnt += m;
    ssum = fmaf(m, hb[(size_t)q*RSn], ssum);
  }
  pooled[(bb*Pn + p)*RSn + t] = (cnt > 0.f) ? ssum / cnt : 0.f;
  if (t == 0) flags[bb*Pn + p] = (cnt > 0.f) ? 1 : 0;
}

// =====================================================================
// D2: k_mid — blocks [0,8192): pool (feat+pos)*(1-mask) -> ATb bf16 + invmp
//             blocks [8192,8240): query tokens + LN -> qt
// =====================================================================
__global__ void k_mid(const float* f0, const float* p0, const void* m0,
                      const float* f1, const float* p1, const void* m1,
                      const float* f2, const float* p2, const void* m2,
                      const float* f3, const float* p3, const void* m3,
                      const int* __restrict__ det, __hip_bfloat16* ATb, float* invmp,
                      const float* __restrict__ lq, const float* __restrict__ Wq,
                      const float* __restrict__ bq, const float* __restrict__ qng,
                      const float* __restrict__ qnb, const float* __restrict__ pooled,
                      const int* __restrict__ flags, float* qt){
  int bx = blockIdx.x;
  if (bx < 8192){
    int s = bx >> 11, b = (bx >> 8) & 7, c = bx & 255;
    const float* F; const float* Pp; const void* M; int H, SB;
    if (s == 0){ F=f0; Pp=p0; M=m0; H=64; SB=0;     }
    else if (s == 1){ F=f1; Pp=p1; M=m1; H=32; SB=8192;  }
    else if (s == 2){ F=f2; Pp=p2; M=m2; H=16; SB=10240; }
    else            { F=f3; Pp=p3; M=m3; H=8;  SB=10752; }
    int OW = H >> 1, T = OW * OW;
    int OW2 = OW >> 1, T2 = T >> 1;         // two tokens per thread (OW>=4 always)
    int mode = (det[0] == 0) ? 0 : ((det[1] == 0) ? 2 : 1);
    const float* Fb = F + (size_t)(b*256 + c)*H*H;
    const float* Pb = Pp + (size_t)(b*256 + c)*H*H;
    int mbase = b*H*H;
    for (int tk = threadIdx.x; tk < T2; tk += 256){
      int ph = tk / OW2, pwp = tk - ph*OW2;
      int i00 = (ph*2)*H + pwp*4;
      float4 fa = *(const float4*)(Fb + i00);
      float4 fb2 = *(const float4*)(Fb + i00 + H);
      float4 pa = *(const float4*)(Pb + i00);
      float4 pb2 = *(const float4*)(Pb + i00 + H);
      float wa[4], wbm[4];
      if (mode == 0){
        int4 ma = *(const int4*)((const int*)M + mbase + i00);
        int4 mb = *(const int4*)((const int*)M + mbase + i00 + H);
        wa[0] = ma.x ? 0.f:1.f; wa[1] = ma.y ? 0.f:1.f; wa[2] = ma.z ? 0.f:1.f; wa[3] = ma.w ? 0.f:1.f;
        wbm[0] = mb.x ? 0.f:1.f; wbm[1] = mb.y ? 0.f:1.f; wbm[2] = mb.z ? 0.f:1.f; wbm[3] = mb.w ? 0.f:1.f;
      } else if (mode == 1){
        const unsigned char* Mb = (const unsigned char*)M + mbase;
        uchar4 ma = *(const uchar4*)(Mb + i00);
        uchar4 mb = *(const uchar4*)(Mb + i00 + H);
        wa[0] = ma.x ? 0.f:1.f; wa[1] = ma.y ? 0.f:1.f; wa[2] = ma.z ? 0.f:1.f; wa[3] = ma.w ? 0.f:1.f;
        wbm[0] = mb.x ? 0.f:1.f; wbm[1] = mb.y ? 0.f:1.f; wbm[2] = mb.z ? 0.f:1.f; wbm[3] = mb.w ? 0.f:1.f;
      } else {
        float4 ma = *(const float4*)((const float*)M + mbase + i00);
        float4 mb = *(const float4*)((const float*)M + mbase + i00 + H);
        wa[0] = 1.f-ma.x; wa[1] = 1.f-ma.y; wa[2] = 1.f-ma.z; wa[3] = 1.f-ma.w;
        wbm[0] = 1.f-mb.x; wbm[1] = 1.f-mb.y; wbm[2] = 1.f-mb.z; wbm[3] = 1.f-mb.w;
      }
      float ff[4] = {fa.x+pa.x, fa.y+pa.y, fa.z+pa.z, fa.w+pa.w};
      float gg[4] = {fb2.x+pb2.x, fb2.y+pb2.y, fb2.z+pb2.z, fb2.w+pb2.w};
      unsigned int packed;
      float im2[2];
      #pragma unroll
      for (int u = 0; u < 2; ++u){
        float xs = ff[u*2]*wa[u*2] + ff[u*2+1]*wa[u*2+1] + gg[u*2]*wbm[u*2] + gg[u*2+1]*wbm[u*2+1];
        float msum = wa[u*2] + wa[u*2+1] + wbm[u*2] + wbm[u*2+1];
        float mp = fmaxf(msum * 0.25f, 1e-6f);
        float im = 1.f / mp;
        im2[u] = im;
        union { float f; unsigned int i; } cv; cv.f = xs * 0.25f * im;
        unsigned int r = (cv.i + 0x7FFF + ((cv.i >> 16) & 1)) >> 16;   // RNE bf16
        if (u == 0) packed = r; else packed |= (r << 16);
      }
      int mIdx = SB + b*T + tk*2;
      *(unsigned int*)((unsigned short*)ATb + (size_t)c*MTOT + mIdx) = packed;
      if (c == 0){ invmp[mIdx] = im2[0]; invmp[mIdx+1] = im2[1]; }
    }
    return;
  }
  // ---- query tokens + LN
  __shared__ float s1[4], s2[4];
  int qbx = bx - 8192;
  int b = qbx / 6, j = qbx % 6;
  int t = threadIdx.x;
  float v0 = lq[j*QSn + t], v1 = lq[j*QSn + t + 256], v2 = lq[j*QSn + t + 512];
  int any = flags[b*Pn] | flags[b*Pn+1] | flags[b*Pn+2] | flags[b*Pn+3] | flags[b*Pn+4];
  if (j > 0 && any){
    const float* pp = pooled + (b*Pn + (j-1))*RSn;
    float a0 = 0.f, a1 = 0.f, a2 = 0.f;
    for (int c = 0; c < RSn; ++c){
      float pv = pp[c];
      a0 = fmaf(pv, Wq[c*QSn + t      ], a0);
      a1 = fmaf(pv, Wq[c*QSn + t + 256], a1);
      a2 = fmaf(pv, Wq[c*QSn + t + 512], a2);
    }
    v0 += a0 + bq[t]; v1 += a1 + bq[t+256]; v2 += a2 + bq[t+512];
  }
  float sm = v0 + v1 + v2, sq = v0*v0 + v1*v1 + v2*v2;
  sm = wred(sm); sq = wred(sq);
  int wid = t >> 6, lane = t & 63;
  if (lane == 0){ s1[wid] = sm; s2[wid] = sq; }
  __syncthreads();
  float S  = s1[0] + s1[1] + s1[2] + s1[3];
  float SQ = s2[0] + s2[1] + s2[2] + s2[3];
  float mu = S * (1.f/QSn), var = SQ * (1.f/QSn) - mu*mu;
  float rs = rsqrtf(var + 1e-5f);
  float* o = qt + (b*6 + j)*QSn;
  o[t      ] = (v0 - mu)*rs*qng[t      ] + qnb[t      ];
  o[t + 256] = (v1 - mu)*rs*qng[t + 256] + qnb[t + 256];
  o[t + 512] = (v2 - mu)*rs*qng[t + 512] + qnb[t + 512];
}

// =====================================================================
// D3: transpose ATb[k][m] -> Am[m][k] (bf16), 64x64 tiles via LDS
// =====================================================================
__global__ void k_tr(const short* __restrict__ ATb, short* __restrict__ Am){
  __shared__ short lds[64][65];
  int mt = blockIdx.x >> 2, kt = blockIdx.x & 3;
  int m0 = mt*64, k0 = kt*64;
  int t = threadIdx.x;
  #pragma unroll
  for (int i = 0; i < 16; ++i){
    int idx = t + i*256;
    int k = idx >> 6, m = idx & 63;
    lds[m][k] = ATb[(size_t)(k0+k)*MTOT + m0 + m];
  }
  __syncthreads();
  #pragma unroll
  for (int i = 0; i < 16; ++i){
    int idx = t + i*256;
    int m = idx >> 6, k = idx & 63;
    Am[(size_t)(m0+m)*256 + k0 + k] = lds[m][k];
  }
}

// =====================================================================
// D4: Stage A GEMM — blocks = 680 m-tiles x 2 n-halves. 256 thr = 4 waves.
// Wave = 16m x 96n (6 frags). 2-kc-deep register ping-pong prefetch.
// Writes P (bf16) + bias, and per-row (sum,sq) partials via atomics.
// =====================================================================
__global__ __launch_bounds__(256, 4) void k_gemm(
    const short* __restrict__ Am, const short* __restrict__ Wb,
    const float* __restrict__ invmp,
    const float* cb0, const float* cb1, const float* cb2, const float* cb3,
    __hip_bfloat16* __restrict__ Pb, float* __restrict__ rowsum, float* __restrict__ rowsq){
  __shared__ float lsum[4][16], lsq[4][16];
  int blk = blockIdx.x;
  int mt = blk >> 1, nhalf = blk & 1;
  int m0 = mt * 16;
  int s;
  if (m0 < 8192) s = 0;
  else if (m0 < 10240) s = 1;
  else if (m0 < 10752) s = 2;
  else s = 3;
  const float* CB = (s==0)?cb0:(s==1)?cb1:(s==2)?cb2:cb3;

  int t = threadIdx.x;
  int wid = t >> 6, l = t & 63;
  int lm = l & 15, lk = l >> 4;
  int nfb = nhalf*24 + wid*6;              // frag range [nfb, nfb+6)
  const short* Arow  = Am + (size_t)(m0 + lm)*256 + lk*8;
  const short* Bbase = Wb + (size_t)s*768*256 + (size_t)(nfb*16 + lm)*256 + lk*8;

  float4v acc[6];
  #pragma unroll
  for (int nf = 0; nf < 6; ++nf) acc[nf] = (float4v){0.f,0.f,0.f,0.f};

  short8 aA = *(const short8*)(Arow);
  short8 aB = *(const short8*)(Arow + 32);
  short8 bA[6], bB[6];
  #pragma unroll
  for (int nf = 0; nf < 6; ++nf){
    bA[nf] = *(const short8*)(Bbase + (size_t)nf*4096);
    bB[nf] = *(const short8*)(Bbase + 32 + (size_t)nf*4096);
  }
  #pragma unroll 1
  for (int kc = 0; kc < 8; kc += 2){
    #pragma unroll
    for (int nf = 0; nf < 6; ++nf)
      acc[nf] = __builtin_amdgcn_mfma_f32_16x16x32_bf16(aA, bA[nf], acc[nf], 0, 0, 0);
    if (kc + 2 < 8){
      aA = *(const short8*)(Arow + (kc+2)*32);
      #pragma unroll
      for (int nf = 0; nf < 6; ++nf)
        bA[nf] = *(const short8*)(Bbase + (kc+2)*32 + (size_t)nf*4096);
    }
    #pragma unroll
    for (int nf = 0; nf < 6; ++nf)
      acc[nf] = __builtin_amdgcn_mfma_f32_16x16x32_bf16(aB, bB[nf], acc[nf], 0, 0, 0);
    if (kc + 3 < 8){
      aB = *(const short8*)(Arow + (kc+3)*32);
      #pragma unroll
      for (int nf = 0; nf < 6; ++nf)
        bB[nf] = *(const short8*)(Bbase + (kc+3)*32 + (size_t)nf*4096);
    }
  }

  // ---- epilogue: bias, store P bf16, partial row stats
  float im[4];
  #pragma unroll
  for (int r = 0; r < 4; ++r) im[r] = invmp[m0 + lk*4 + r];
  float sum[4] = {0,0,0,0}, sq[4] = {0,0,0,0};
  #pragma unroll
  for (int nf = 0; nf < 6; ++nf){
    float cbv = CB[(nfb+nf)*16 + lm];
    #pragma unroll
    for (int r = 0; r < 4; ++r){
      float p = acc[nf][r] + cbv*im[r];
      sum[r] += p;
      sq[r] = fmaf(p, p, sq[r]);
      Pb[(size_t)(m0 + lk*4 + r)*768 + (nfb+nf)*16 + lm] = __float2bfloat16(p);
    }
  }
  #pragma unroll
  for (int r = 0; r < 4; ++r){
    #pragma unroll
    for (int off = 1; off < 16; off <<= 1){
      sum[r] += __shfl_xor(sum[r], off);
      sq[r]  += __shfl_xor(sq[r],  off);
    }
  }
  if (lm == 0){
    #pragma unroll
    for (int r = 0; r < 4; ++r){ lsum[wid][lk*4+r] = sum[r]; lsq[wid][lk*4+r] = sq[r]; }
  }
  __syncthreads();
  if (t < 16){
    float S  = lsum[0][t] + lsum[1][t] + lsum[2][t] + lsum[3][t];
    float SQ = lsq[0][t]  + lsq[1][t]  + lsq[2][t]  + lsq[3][t];
    atomicAdd(&rowsum[m0 + t], S);
    atomicAdd(&rowsq[m0 + t], SQ);
  }
}

// =====================================================================
// D5: Stage B — LN + token-sum. 680 blocks x 256 thr; block = 16 rows.
// Reads bf16 P + rowstats, accumulates ctxsum via LDS combine + atomics.
// =====================================================================
__global__ void k_lnsum(const unsigned short* __restrict__ Pb,
    const float* __restrict__ rowsum, const float* __restrict__ rowsq,
    const float* lg0, const float* lb0, const float* lg1, const float* lb1,
    const float* lg2, const float* lb2, const float* lg3, const float* lb3,
    float* __restrict__ ctxsum){
  __shared__ float lds[4][768];
  int m0 = blockIdx.x * 16;
  int s, b;
  if (m0 < 8192){ s=0; b=m0>>10; }
  else if (m0 < 10240){ s=1; b=(m0-8192)>>8; }
  else if (m0 < 10752){ s=2; b=(m0-10240)>>6; }
  else { s=3; b=(m0-10752)>>4; }
  const float *LG, *LB;
  if (s==0){ LG=lg0; LB=lb0; }
  else if (s==1){ LG=lg1; LB=lb1; }
  else if (s==2){ LG=lg2; LB=lb2; }
  else { LG=lg3; LB=lb3; }

  int t = threadIdx.x;
  int wid = t >> 6, l = t & 63;
  float acc[12];
  #pragma unroll
  for (int j = 0; j < 12; ++j) acc[j] = 0.f;
  #pragma unroll
  for (int r = 0; r < 4; ++r){
    int row = m0 + wid*4 + r;
    float mu = rowsum[row] * (1.f/768.f);
    float var = rowsq[row] * (1.f/768.f) - mu*mu;
    float rs = rsqrtf(var + 1e-5f);
    const unsigned short* prow = Pb + (size_t)row*768;
    #pragma unroll
    for (int jj = 0; jj < 3; ++jj){
      ushort4 pv = *(const ushort4*)(prow + l*4 + jj*256);
      acc[jj*4+0] += (bf2f(pv.x) - mu)*rs;
      acc[jj*4+1] += (bf2f(pv.y) - mu)*rs;
      acc[jj*4+2] += (bf2f(pv.z) - mu)*rs;
      acc[jj*4+3] += (bf2f(pv.w) - mu)*rs;
    }
  }
  #pragma unroll
  for (int jj = 0; jj < 3; ++jj){
    #pragma unroll
    for (int q = 0; q < 4; ++q)
      lds[wid][l*4 + jj*256 + q] = acc[jj*4+q];
  }
  __syncthreads();
  #pragma unroll
  for (int cc = 0; cc < 3; ++cc){
    int n = t + cc*256;
    float tot = lds[0][n] + lds[1][n] + lds[2][n] + lds[3][n];
    atomicAdd(&ctxsum[b*768 + n], tot*LG[n] + 16.f*LB[n]);
  }
}

// =====================================================================
// D6: tail — one block per batch (768 thr): v -> h -> out
// =====================================================================
__global__ void k_tail(const float* __restrict__ qt, const float* __restrict__ ctxsum,
                       const float* __restrict__ W1, const float* __restrict__ b1,
                       const float* __restrict__ W2, const float* __restrict__ b2,
                       float* __restrict__ out){
  __shared__ float v[768], h[768];
  int b = blockIdx.x, t = threadIdx.x;
  const float* q = qt + (size_t)b*6*768;
  float pm = q[768+t] + q[2*768+t] + q[3*768+t] + q[4*768+t] + q[5*768+t];
  v[t] = q[t] + 0.2f*pm + 2.f*ctxsum[b*768 + t]*(1.f/1360.f);
  __syncthreads();
  float acc = b1[t];
  #pragma unroll 4
  for (int c = 0; c < 768; ++c) acc = fmaf(v[c], W1[c*768 + t], acc);
  h[t] = fmaxf(acc, 0.f);
  __syncthreads();
  if (t < NCn){
    float a2 = b2[t];
    #pragma unroll 4
    for (int c = 0; c < 768; ++c) a2 = fmaf(h[c], W2[c*NCn + t], a2);
    out[b*NCn + t] = a2;
  }
}

extern "C" void kernel_launch(void* const* d_in, const int* in_sizes, int n_in,
                              void* d_out, int out_size, void* d_ws, size_t ws_size,
                              hipStream_t stream){
  const float* pl = (const float*)d_in[0];
  const float* hs = (const float*)d_in[2];
  const float* feat[4]; const float* pos[4]; const void* mask[4];
  const float* cw[4]; const float* cb[4]; const float* lg[4]; const float* lb[4];
  for (int s = 0; s < 4; ++s){
    int base = 3 + 7*s;
    feat[s] = (const float*)d_in[base];
    pos[s]  = (const float*)d_in[base+1];
    mask[s] = d_in[base+2];
    cw[s]   = (const float*)d_in[base+3];
    cb[s]   = (const float*)d_in[base+4];
    lg[s]   = (const float*)d_in[base+5];
    lb[s]   = (const float*)d_in[base+6];
  }
  const float* lq  = (const float*)d_in[31];
  const float* Wq  = (const float*)d_in[32];
  const float* bq  = (const float*)d_in[33];
  const float* qng = (const float*)d_in[34];
  const float* qnb = (const float*)d_in[35];
  const float* W1  = (const float*)d_in[36];
  const float* b1  = (const float*)d_in[37];
  const float* W2  = (const float*)d_in[38];
  const float* b2  = (const float*)d_in[39];
  float* out = (float*)d_out;

  // ---- workspace layout (~30 MB)
  short* ATb    = (short*)d_ws;                        // 256*10880 bf16
  short* Am     = ATb + (size_t)256*MTOT;              // 10880*256 bf16
  short* Wb     = Am + (size_t)MTOT*256;               // 4*768*256 bf16
  short* Pb     = Wb + (size_t)4*768*256;              // 10880*768 bf16
  float* invmp  = (float*)(Pb + (size_t)MTOT*768);     // 10880
  float* pooled = invmp + MTOT;                        // 40*256
  float* qt     = pooled + 40*RSn;                     // 8*6*768
  // ---- zeroed region (contiguous): ctxsum | rowsum | rowsq | det
  float* ctxsum = qt + Bn*6*QSn;                       // 8*768
  float* rowsum = ctxsum + Bn*QSn;                     // 10880
  float* rowsq  = rowsum + MTOT;                       // 10880
  int*   det    = (int*)(rowsq + MTOT);                // 4 ints
  int*   flags  = det + 4;                             // 40 ints

  size_t zbytes = (size_t)(Bn*QSn + 2*MTOT)*sizeof(float) + 4*sizeof(int);
  hipMemsetAsync(ctxsum, 0, zbytes, stream);
  k_front<<<840, 256, 0, stream>>>(cw[0], cw[1], cw[2], cw[3], (__hip_bfloat16*)Wb,
                                   (const int*)mask[0], det, pl, hs, pooled, flags);
  k_mid<<<8240, 256, 0, stream>>>(feat[0], pos[0], mask[0],
                                  feat[1], pos[1], mask[1],
                                  feat[2], pos[2], mask[2],
                                  feat[3], pos[3], mask[3],
                                  det, (__hip_bfloat16*)ATb, invmp,
                                  lq, Wq, bq, qng, qnb, pooled, flags, qt);
  k_tr<<<170*4, 256, 0, stream>>>(ATb, Am);
  k_gemm<<<680*2, 256, 0, stream>>>(Am, Wb, invmp,
                                    cb[0], cb[1], cb[2], cb[3],
                                    (__hip_bfloat16*)Pb, rowsum, rowsq);
  k_lnsum<<<680, 256, 0, stream>>>((const unsigned short*)Pb, rowsum, rowsq,
                                   lg[0], lb[0], lg[1], lb[1],
                                   lg[2], lb[2], lg[3], lb[3], ctxsum);
  k_tail<<<Bn, 768, 0, stream>>>(qt, ctxsum, W1, b1, W2, b2, out);
}

// Round 5
// 310.618 us; speedup vs baseline: 1.4785x; 1.4785x over previous
//
#include <hip/hip_runtime.h>
#include <hip/hip_bf16.h>

#define Bn 8
#define Qn 300
#define Pn 5
#define RSn 256
#define QSn 768
#define NCn 396
#define MTOT 10880
#define THRL -1.3862943611198906f   // log(0.2/0.8): sigmoid(x)>0.2 <=> x>THRL

typedef __attribute__((ext_vector_type(8))) short short8;
typedef __attribute__((ext_vector_type(4))) float float4v;

__device__ inline float wred(float v){
  #pragma unroll
  for (int off = 32; off; off >>= 1) v += __shfl_xor(v, off);
  return v;
}

__device__ inline float bf2f(unsigned short u){
  union { unsigned int i; float f; } c; c.i = ((unsigned int)u) << 16; return c.f;
}

// =====================================================================
// D1: k_front — blocks [0,768): convW f32->bf16 ; [768,800): mask detect ;
//               [800,840): query pooling
// =====================================================================
__global__ void k_front(const float* cw0, const float* cw1, const float* cw2, const float* cw3,
                        __hip_bfloat16* Wb, const int* __restrict__ m0, int* det,
                        const float* __restrict__ pl, const float* __restrict__ hs,
                        float* pooled, int* flags){
  int bx = blockIdx.x;
  if (bx < 768){
    int s = bx / 192;
    int off = (bx % 192)*1024 + threadIdx.x*4;
    const float* src = (s==0)?cw0:(s==1)?cw1:(s==2)?cw2:cw3;
    __hip_bfloat16* dst = Wb + (size_t)s*768*256;
    #pragma unroll
    for (int i = 0; i < 4; ++i) dst[off+i] = __float2bfloat16(src[off+i]);
    return;
  }
  if (bx < 800){
    int i = (bx - 768) * 256 + threadIdx.x;   // 8192 ints = 32KB, safe under all layouts
    int v = m0[i];
    if (v != 0 && v != 1) atomicOr(&det[0], 1);
    if (v != 0 && v != 0x3F800000) atomicOr(&det[1], 1);
    return;
  }
  // ---- query pooling
  __shared__ float msk[Qn];
  int bb = (bx - 800) / Pn, p = (bx - 800) % Pn;
  int t = threadIdx.x;
  for (int q = t; q < Qn; q += 256)
    msk[q] = (pl[(bb*Qn + q)*Pn + p] > THRL) ? 1.f : 0.f;
  __syncthreads();
  const float* hb = hs + (size_t)bb*Qn*RSn + t;
  float ssum = 0.f, cnt = 0.f;
  for (int q = 0; q < Qn; ++q){
    float m = msk[q];
    cnt += m;
    ssum = fmaf(m, hb[(size_t)q*RSn], ssum);
  }
  pooled[(bb*Pn + p)*RSn + t] = (cnt > 0.f) ? ssum / cnt : 0.f;
  if (t == 0) flags[bb*Pn + p] = (cnt > 0.f) ? 1 : 0;
}

// =====================================================================
// D2: k_mid — blocks [0,8192): pool (feat+pos)*(1-mask) -> ATb bf16 + invmp
//             blocks [8192,8240): query tokens + LN -> qt
// =====================================================================
__global__ void k_mid(const float* f0, const float* p0, const void* m0,
                      const float* f1, const float* p1, const void* m1,
                      const float* f2, const float* p2, const void* m2,
                      const float* f3, const float* p3, const void* m3,
                      const int* __restrict__ det, __hip_bfloat16* ATb, float* invmp,
                      const float* __restrict__ lq, const float* __restrict__ Wq,
                      const float* __restrict__ bq, const float* __restrict__ qng,
                      const float* __restrict__ qnb, const float* __restrict__ pooled,
                      const int* __restrict__ flags, float* qt){
  int bx = blockIdx.x;
  if (bx < 8192){
    int s = bx >> 11, b = (bx >> 8) & 7, c = bx & 255;
    const float* F; const float* Pp; const void* M; int H, SB;
    if (s == 0){ F=f0; Pp=p0; M=m0; H=64; SB=0;     }
    else if (s == 1){ F=f1; Pp=p1; M=m1; H=32; SB=8192;  }
    else if (s == 2){ F=f2; Pp=p2; M=m2; H=16; SB=10240; }
    else            { F=f3; Pp=p3; M=m3; H=8;  SB=10752; }
    int OW = H >> 1, T = OW * OW;
    int OW2 = OW >> 1, T2 = T >> 1;         // two tokens per thread (OW>=4 always)
    int mode = (det[0] == 0) ? 0 : ((det[1] == 0) ? 2 : 1);
    const float* Fb = F + (size_t)(b*256 + c)*H*H;
    const float* Pb = Pp + (size_t)(b*256 + c)*H*H;
    int mbase = b*H*H;
    for (int tk = threadIdx.x; tk < T2; tk += 256){
      int ph = tk / OW2, pwp = tk - ph*OW2;
      int i00 = (ph*2)*H + pwp*4;
      float4 fa = *(const float4*)(Fb + i00);
      float4 fb2 = *(const float4*)(Fb + i00 + H);
      float4 pa = *(const float4*)(Pb + i00);
      float4 pb2 = *(const float4*)(Pb + i00 + H);
      float wa[4], wbm[4];
      if (mode == 0){
        int4 ma = *(const int4*)((const int*)M + mbase + i00);
        int4 mb = *(const int4*)((const int*)M + mbase + i00 + H);
        wa[0] = ma.x ? 0.f:1.f; wa[1] = ma.y ? 0.f:1.f; wa[2] = ma.z ? 0.f:1.f; wa[3] = ma.w ? 0.f:1.f;
        wbm[0] = mb.x ? 0.f:1.f; wbm[1] = mb.y ? 0.f:1.f; wbm[2] = mb.z ? 0.f:1.f; wbm[3] = mb.w ? 0.f:1.f;
      } else if (mode == 1){
        const unsigned char* Mb = (const unsigned char*)M + mbase;
        uchar4 ma = *(const uchar4*)(Mb + i00);
        uchar4 mb = *(const uchar4*)(Mb + i00 + H);
        wa[0] = ma.x ? 0.f:1.f; wa[1] = ma.y ? 0.f:1.f; wa[2] = ma.z ? 0.f:1.f; wa[3] = ma.w ? 0.f:1.f;
        wbm[0] = mb.x ? 0.f:1.f; wbm[1] = mb.y ? 0.f:1.f; wbm[2] = mb.z ? 0.f:1.f; wbm[3] = mb.w ? 0.f:1.f;
      } else {
        float4 ma = *(const float4*)((const float*)M + mbase + i00);
        float4 mb = *(const float4*)((const float*)M + mbase + i00 + H);
        wa[0] = 1.f-ma.x; wa[1] = 1.f-ma.y; wa[2] = 1.f-ma.z; wa[3] = 1.f-ma.w;
        wbm[0] = 1.f-mb.x; wbm[1] = 1.f-mb.y; wbm[2] = 1.f-mb.z; wbm[3] = 1.f-mb.w;
      }
      float ff[4] = {fa.x+pa.x, fa.y+pa.y, fa.z+pa.z, fa.w+pa.w};
      float gg[4] = {fb2.x+pb2.x, fb2.y+pb2.y, fb2.z+pb2.z, fb2.w+pb2.w};
      unsigned int packed;
      float im2[2];
      #pragma unroll
      for (int u = 0; u < 2; ++u){
        float xs = ff[u*2]*wa[u*2] + ff[u*2+1]*wa[u*2+1] + gg[u*2]*wbm[u*2] + gg[u*2+1]*wbm[u*2+1];
        float msum = wa[u*2] + wa[u*2+1] + wbm[u*2] + wbm[u*2+1];
        float mp = fmaxf(msum * 0.25f, 1e-6f);
        float im = 1.f / mp;
        im2[u] = im;
        union { float f; unsigned int i; } cv; cv.f = xs * 0.25f * im;
        unsigned int r = (cv.i + 0x7FFF + ((cv.i >> 16) & 1)) >> 16;   // RNE bf16
        if (u == 0) packed = r; else packed |= (r << 16);
      }
      int mIdx = SB + b*T + tk*2;
      *(unsigned int*)((unsigned short*)ATb + (size_t)c*MTOT + mIdx) = packed;
      if (c == 0){ invmp[mIdx] = im2[0]; invmp[mIdx+1] = im2[1]; }
    }
    return;
  }
  // ---- query tokens + LN
  __shared__ float s1[4], s2[4];
  int qbx = bx - 8192;
  int b = qbx / 6, j = qbx % 6;
  int t = threadIdx.x;
  float v0 = lq[j*QSn + t], v1 = lq[j*QSn + t + 256], v2 = lq[j*QSn + t + 512];
  int any = flags[b*Pn] | flags[b*Pn+1] | flags[b*Pn+2] | flags[b*Pn+3] | flags[b*Pn+4];
  if (j > 0 && any){
    const float* pp = pooled + (b*Pn + (j-1))*RSn;
    float a0 = 0.f, a1 = 0.f, a2 = 0.f;
    for (int c = 0; c < RSn; ++c){
      float pv = pp[c];
      a0 = fmaf(pv, Wq[c*QSn + t      ], a0);
      a1 = fmaf(pv, Wq[c*QSn + t + 256], a1);
      a2 = fmaf(pv, Wq[c*QSn + t + 512], a2);
    }
    v0 += a0 + bq[t]; v1 += a1 + bq[t+256]; v2 += a2 + bq[t+512];
  }
  float sm = v0 + v1 + v2, sq = v0*v0 + v1*v1 + v2*v2;
  sm = wred(sm); sq = wred(sq);
  int wid = t >> 6, lane = t & 63;
  if (lane == 0){ s1[wid] = sm; s2[wid] = sq; }
  __syncthreads();
  float S  = s1[0] + s1[1] + s1[2] + s1[3];
  float SQ = s2[0] + s2[1] + s2[2] + s2[3];
  float mu = S * (1.f/QSn), var = SQ * (1.f/QSn) - mu*mu;
  float rs = rsqrtf(var + 1e-5f);
  float* o = qt + (b*6 + j)*QSn;
  o[t      ] = (v0 - mu)*rs*qng[t      ] + qnb[t      ];
  o[t + 256] = (v1 - mu)*rs*qng[t + 256] + qnb[t + 256];
  o[t + 512] = (v2 - mu)*rs*qng[t + 512] + qnb[t + 512];
}

// =====================================================================
// D3: transpose ATb[k][m] -> Am[m][k] (bf16), 64x64 tiles via LDS
// =====================================================================
__global__ void k_tr(const short* __restrict__ ATb, short* __restrict__ Am){
  __shared__ short lds[64][65];
  int mt = blockIdx.x >> 2, kt = blockIdx.x & 3;
  int m0 = mt*64, k0 = kt*64;
  int t = threadIdx.x;
  #pragma unroll
  for (int i = 0; i < 16; ++i){
    int idx = t + i*256;
    int k = idx >> 6, m = idx & 63;
    lds[m][k] = ATb[(size_t)(k0+k)*MTOT + m0 + m];
  }
  __syncthreads();
  #pragma unroll
  for (int i = 0; i < 16; ++i){
    int idx = t + i*256;
    int m = idx >> 6, k = idx & 63;
    Am[(size_t)(m0+m)*256 + k0 + k] = lds[m][k];
  }
}

// =====================================================================
// D4: Stage A GEMM — blocks = 680 m-tiles x 2 n-halves. 256 thr = 4 waves.
// Wave = 16m x 96n (6 frags). 2-kc-deep register ping-pong prefetch.
// Writes P (bf16) + bias, and per-row (sum,sq) partials via atomics.
// =====================================================================
__global__ __launch_bounds__(256, 4) void k_gemm(
    const short* __restrict__ Am, const short* __restrict__ Wb,
    const float* __restrict__ invmp,
    const float* cb0, const float* cb1, const float* cb2, const float* cb3,
    __hip_bfloat16* __restrict__ Pb, float* __restrict__ rowsum, float* __restrict__ rowsq){
  __shared__ float lsum[4][16], lsq[4][16];
  int blk = blockIdx.x;
  int mt = blk >> 1, nhalf = blk & 1;
  int m0 = mt * 16;
  int s;
  if (m0 < 8192) s = 0;
  else if (m0 < 10240) s = 1;
  else if (m0 < 10752) s = 2;
  else s = 3;
  const float* CB = (s==0)?cb0:(s==1)?cb1:(s==2)?cb2:cb3;

  int t = threadIdx.x;
  int wid = t >> 6, l = t & 63;
  int lm = l & 15, lk = l >> 4;
  int nfb = nhalf*24 + wid*6;              // frag range [nfb, nfb+6)
  const short* Arow  = Am + (size_t)(m0 + lm)*256 + lk*8;
  const short* Bbase = Wb + (size_t)s*768*256 + (size_t)(nfb*16 + lm)*256 + lk*8;

  float4v acc[6];
  #pragma unroll
  for (int nf = 0; nf < 6; ++nf) acc[nf] = (float4v){0.f,0.f,0.f,0.f};

  short8 aA = *(const short8*)(Arow);
  short8 aB = *(const short8*)(Arow + 32);
  short8 bA[6], bB[6];
  #pragma unroll
  for (int nf = 0; nf < 6; ++nf){
    bA[nf] = *(const short8*)(Bbase + (size_t)nf*4096);
    bB[nf] = *(const short8*)(Bbase + 32 + (size_t)nf*4096);
  }
  #pragma unroll 1
  for (int kc = 0; kc < 8; kc += 2){
    #pragma unroll
    for (int nf = 0; nf < 6; ++nf)
      acc[nf] = __builtin_amdgcn_mfma_f32_16x16x32_bf16(aA, bA[nf], acc[nf], 0, 0, 0);
    if (kc + 2 < 8){
      aA = *(const short8*)(Arow + (kc+2)*32);
      #pragma unroll
      for (int nf = 0; nf < 6; ++nf)
        bA[nf] = *(const short8*)(Bbase + (kc+2)*32 + (size_t)nf*4096);
    }
    #pragma unroll
    for (int nf = 0; nf < 6; ++nf)
      acc[nf] = __builtin_amdgcn_mfma_f32_16x16x32_bf16(aB, bB[nf], acc[nf], 0, 0, 0);
    if (kc + 3 < 8){
      aB = *(const short8*)(Arow + (kc+3)*32);
      #pragma unroll
      for (int nf = 0; nf < 6; ++nf)
        bB[nf] = *(const short8*)(Bbase + (kc+3)*32 + (size_t)nf*4096);
    }
  }

  // ---- epilogue: bias, store P bf16, partial row stats
  float im[4];
  #pragma unroll
  for (int r = 0; r < 4; ++r) im[r] = invmp[m0 + lk*4 + r];
  float sum[4] = {0,0,0,0}, sq[4] = {0,0,0,0};
  #pragma unroll
  for (int nf = 0; nf < 6; ++nf){
    float cbv = CB[(nfb+nf)*16 + lm];
    #pragma unroll
    for (int r = 0; r < 4; ++r){
      float p = acc[nf][r] + cbv*im[r];
      sum[r] += p;
      sq[r] = fmaf(p, p, sq[r]);
      Pb[(size_t)(m0 + lk*4 + r)*768 + (nfb+nf)*16 + lm] = __float2bfloat16(p);
    }
  }
  #pragma unroll
  for (int r = 0; r < 4; ++r){
    #pragma unroll
    for (int off = 1; off < 16; off <<= 1){
      sum[r] += __shfl_xor(sum[r], off);
      sq[r]  += __shfl_xor(sq[r],  off);
    }
  }
  if (lm == 0){
    #pragma unroll
    for (int r = 0; r < 4; ++r){ lsum[wid][lk*4+r] = sum[r]; lsq[wid][lk*4+r] = sq[r]; }
  }
  __syncthreads();
  if (t < 16){
    float S  = lsum[0][t] + lsum[1][t] + lsum[2][t] + lsum[3][t];
    float SQ = lsq[0][t]  + lsq[1][t]  + lsq[2][t]  + lsq[3][t];
    atomicAdd(&rowsum[m0 + t], S);
    atomicAdd(&rowsq[m0 + t], SQ);
  }
}

// =====================================================================
// D5: Stage B — LN + token-sum. 680 blocks x 256 thr; block = 16 rows.
// =====================================================================
__global__ void k_lnsum(const unsigned short* __restrict__ Pb,
    const float* __restrict__ rowsum, const float* __restrict__ rowsq,
    const float* lg0, const float* lb0, const float* lg1, const float* lb1,
    const float* lg2, const float* lb2, const float* lg3, const float* lb3,
    float* __restrict__ ctxsum){
  __shared__ float lds[4][768];
  int m0 = blockIdx.x * 16;
  int s, b;
  if (m0 < 8192){ s=0; b=m0>>10; }
  else if (m0 < 10240){ s=1; b=(m0-8192)>>8; }
  else if (m0 < 10752){ s=2; b=(m0-10240)>>6; }
  else { s=3; b=(m0-10752)>>4; }
  const float *LG, *LB;
  if (s==0){ LG=lg0; LB=lb0; }
  else if (s==1){ LG=lg1; LB=lb1; }
  else if (s==2){ LG=lg2; LB=lb2; }
  else { LG=lg3; LB=lb3; }

  int t = threadIdx.x;
  int wid = t >> 6, l = t & 63;
  float acc[12];
  #pragma unroll
  for (int j = 0; j < 12; ++j) acc[j] = 0.f;
  #pragma unroll
  for (int r = 0; r < 4; ++r){
    int row = m0 + wid*4 + r;
    float mu = rowsum[row] * (1.f/768.f);
    float var = rowsq[row] * (1.f/768.f) - mu*mu;
    float rs = rsqrtf(var + 1e-5f);
    const unsigned short* prow = Pb + (size_t)row*768;
    #pragma unroll
    for (int jj = 0; jj < 3; ++jj){
      ushort4 pv = *(const ushort4*)(prow + l*4 + jj*256);
      acc[jj*4+0] += (bf2f(pv.x) - mu)*rs;
      acc[jj*4+1] += (bf2f(pv.y) - mu)*rs;
      acc[jj*4+2] += (bf2f(pv.z) - mu)*rs;
      acc[jj*4+3] += (bf2f(pv.w) - mu)*rs;
    }
  }
  #pragma unroll
  for (int jj = 0; jj < 3; ++jj){
    #pragma unroll
    for (int q = 0; q < 4; ++q)
      lds[wid][l*4 + jj*256 + q] = acc[jj*4+q];
  }
  __syncthreads();
  #pragma unroll
  for (int cc = 0; cc < 3; ++cc){
    int n = t + cc*256;
    float tot = lds[0][n] + lds[1][n] + lds[2][n] + lds[3][n];
    atomicAdd(&ctxsum[b*768 + n], tot*LG[n] + 16.f*LB[n]);
  }
}

// =====================================================================
// D6: k_hpre — hpre = v @ W1 (+b1), split-K, v rebuilt per-block from qt+ctxsum.
// Grid: 12 n-chunks x 4 k-chunks = 48 blocks, 256 thr.
// Thread: o = n0 + (t&63); b in {t>>6, (t>>6)+4}. relu deferred to consumer.
// =====================================================================
__global__ void k_hpre(const float* __restrict__ qt, const float* __restrict__ ctxsum,
                       const float* __restrict__ W1, const float* __restrict__ b1,
                       float* __restrict__ hpre){
  __shared__ float vsh[Bn][192];
  int nc = blockIdx.x % 12, kc = blockIdx.x / 12;
  int n0 = nc*64, c0 = kc*192;
  int t = threadIdx.x;
  for (int i = t; i < Bn*192; i += 256){
    int b = i / 192, cl = i - b*192;
    int c = c0 + cl;
    const float* q = qt + (size_t)b*6*768;
    float pm = q[768+c] + q[2*768+c] + q[3*768+c] + q[4*768+c] + q[5*768+c];
    vsh[b][cl] = q[c] + 0.2f*pm + ctxsum[b*768 + c]*(1.f/680.f);
  }
  __syncthreads();
  int ol = t & 63, bg = t >> 6;
  int o = n0 + ol;
  float acc0 = 0.f, acc1 = 0.f;
  const float* w = W1 + (size_t)c0*768 + o;
  #pragma unroll 8
  for (int cl = 0; cl < 192; ++cl){
    float wv = w[(size_t)cl*768];
    acc0 = fmaf(vsh[bg][cl],   wv, acc0);
    acc1 = fmaf(vsh[bg+4][cl], wv, acc1);
  }
  if (kc == 0){ float bv = b1[o]; acc0 += bv; acc1 += bv; }
  atomicAdd(&hpre[bg*768 + o], acc0);
  atomicAdd(&hpre[(bg+4)*768 + o], acc1);
}

// =====================================================================
// D7: k_out — out = relu(hpre) @ W2 + b2, split-K.
// Grid: 7 n-chunks x 4 k-chunks = 28 blocks, 256 thr. d_out pre-zeroed.
// =====================================================================
__global__ void k_out(const float* __restrict__ hpre, const float* __restrict__ W2,
                      const float* __restrict__ b2, float* __restrict__ out){
  __shared__ float hsh[Bn][192];
  int nc = blockIdx.x % 7, kc = blockIdx.x / 7;
  int n0 = nc*64, c0 = kc*192;
  int t = threadIdx.x;
  for (int i = t; i < Bn*192; i += 256){
    int b = i / 192, cl = i - b*192;
    hsh[b][cl] = fmaxf(hpre[b*768 + c0 + cl], 0.f);
  }
  __syncthreads();
  int ol = t & 63, bg = t >> 6;
  int o = n0 + ol;
  if (o >= NCn) return;
  float acc0 = 0.f, acc1 = 0.f;
  const float* w = W2 + (size_t)c0*NCn + o;
  #pragma unroll 8
  for (int cl = 0; cl < 192; ++cl){
    float wv = w[(size_t)cl*NCn];
    acc0 = fmaf(hsh[bg][cl],   wv, acc0);
    acc1 = fmaf(hsh[bg+4][cl], wv, acc1);
  }
  if (kc == 0){ float bv = b2[o]; acc0 += bv; acc1 += bv; }
  atomicAdd(&out[bg*NCn + o], acc0);
  atomicAdd(&out[(bg+4)*NCn + o], acc1);
}

extern "C" void kernel_launch(void* const* d_in, const int* in_sizes, int n_in,
                              void* d_out, int out_size, void* d_ws, size_t ws_size,
                              hipStream_t stream){
  const float* pl = (const float*)d_in[0];
  const float* hs = (const float*)d_in[2];
  const float* feat[4]; const float* pos[4]; const void* mask[4];
  const float* cw[4]; const float* cb[4]; const float* lg[4]; const float* lb[4];
  for (int s = 0; s < 4; ++s){
    int base = 3 + 7*s;
    feat[s] = (const float*)d_in[base];
    pos[s]  = (const float*)d_in[base+1];
    mask[s] = d_in[base+2];
    cw[s]   = (const float*)d_in[base+3];
    cb[s]   = (const float*)d_in[base+4];
    lg[s]   = (const float*)d_in[base+5];
    lb[s]   = (const float*)d_in[base+6];
  }
  const float* lq  = (const float*)d_in[31];
  const float* Wq  = (const float*)d_in[32];
  const float* bq  = (const float*)d_in[33];
  const float* qng = (const float*)d_in[34];
  const float* qnb = (const float*)d_in[35];
  const float* W1  = (const float*)d_in[36];
  const float* b1  = (const float*)d_in[37];
  const float* W2  = (const float*)d_in[38];
  const float* b2  = (const float*)d_in[39];
  float* out = (float*)d_out;

  // ---- workspace layout (~30 MB)
  short* ATb    = (short*)d_ws;                        // 256*10880 bf16
  short* Am     = ATb + (size_t)256*MTOT;              // 10880*256 bf16
  short* Wb     = Am + (size_t)MTOT*256;               // 4*768*256 bf16
  short* Pb     = Wb + (size_t)4*768*256;              // 10880*768 bf16
  float* invmp  = (float*)(Pb + (size_t)MTOT*768);     // 10880
  float* pooled = invmp + MTOT;                        // 40*256
  float* qt     = pooled + 40*RSn;                     // 8*6*768
  // ---- zeroed region (contiguous): ctxsum | rowsum | rowsq | hpre | det
  float* ctxsum = qt + Bn*6*QSn;                       // 8*768
  float* rowsum = ctxsum + Bn*QSn;                     // 10880
  float* rowsq  = rowsum + MTOT;                       // 10880
  float* hpre   = rowsq + MTOT;                        // 8*768
  int*   det    = (int*)(hpre + Bn*QSn);               // 4 ints
  int*   flags  = det + 4;                             // 40 ints

  size_t zbytes = (size_t)(2*Bn*QSn + 2*MTOT)*sizeof(float) + 4*sizeof(int);
  hipMemsetAsync(ctxsum, 0, zbytes, stream);
  hipMemsetAsync(out, 0, (size_t)Bn*NCn*sizeof(float), stream);
  k_front<<<840, 256, 0, stream>>>(cw[0], cw[1], cw[2], cw[3], (__hip_bfloat16*)Wb,
                                   (const int*)mask[0], det, pl, hs, pooled, flags);
  k_mid<<<8240, 256, 0, stream>>>(feat[0], pos[0], mask[0],
                                  feat[1], pos[1], mask[1],
                                  feat[2], pos[2], mask[2],
                                  feat[3], pos[3], mask[3],
                                  det, (__hip_bfloat16*)ATb, invmp,
                                  lq, Wq, bq, qng, qnb, pooled, flags, qt);
  k_tr<<<170*4, 256, 0, stream>>>(ATb, Am);
  k_gemm<<<680*2, 256, 0, stream>>>(Am, Wb, invmp,
                                    cb[0], cb[1], cb[2], cb[3],
                                    (__hip_bfloat16*)Pb, rowsum, rowsq);
  k_lnsum<<<680, 256, 0, stream>>>((const unsigned short*)Pb, rowsum, rowsq,
                                   lg[0], lb[0], lg[1], lb[1],
                                   lg[2], lb[2], lg[3], lb[3], ctxsum);
  k_hpre<<<48, 256, 0, stream>>>(qt, ctxsum, W1, b1, hpre);
  k_out<<<28, 256, 0, stream>>>(hpre, W2, b2, out);
}